// Round 1
// baseline (1293.052 us; speedup 1.0000x reference)
//
#include <hip/hip_runtime.h>

// ---------------- problem constants (fixed by reference) ----------------
#define N_NODES 100000
#define N_EDGES 1600000
#define NG      512

static __device__ __forceinline__ float lrelu(float v) {
    return v >= 0.0f ? v : 0.01f * v;
}

// ---------------- setup kernels ----------------
__global__ void k_zero_i32(int* __restrict__ p, int n) {
    int i = blockIdx.x * blockDim.x + threadIdx.x;
    if (i < n) p[i] = 0;
}

__global__ void k_copy_i32(const int* __restrict__ s, int* __restrict__ d, int n) {
    int i = blockIdx.x * blockDim.x + threadIdx.x;
    if (i < n) d[i] = s[i];
}

__global__ void k_count(const int* __restrict__ dst, int* __restrict__ counts) {
    int e = blockIdx.x * blockDim.x + threadIdx.x;
    if (e < N_EDGES) atomicAdd(&counts[dst[e]], 1);
}

__global__ void k_dinv(const int* __restrict__ counts, float* __restrict__ dinv) {
    int i = blockIdx.x * blockDim.x + threadIdx.x;
    if (i < N_NODES) dinv[i] = 1.0f / sqrtf((float)(counts[i] + 1)); // +1 self loop
}

// ---------------- exclusive scan (counts -> offsets) ----------------
__global__ void k_scan_block(const int* __restrict__ counts, int* __restrict__ offsets,
                             int* __restrict__ bsums, int n) {
    __shared__ int tmp[1024];
    int gid = blockIdx.x * 1024 + threadIdx.x;
    int v = (gid < n) ? counts[gid] : 0;
    tmp[threadIdx.x] = v;
    __syncthreads();
    for (int off = 1; off < 1024; off <<= 1) {
        int t = (threadIdx.x >= off) ? tmp[threadIdx.x - off] : 0;
        __syncthreads();
        tmp[threadIdx.x] += t;
        __syncthreads();
    }
    if (gid < n) offsets[gid + 1] = tmp[threadIdx.x];
    if (threadIdx.x == 1023) bsums[blockIdx.x] = tmp[1023];
}

__global__ void k_scan_bsums(int* __restrict__ bsums, int nb) {
    if (blockIdx.x == 0 && threadIdx.x == 0) {
        int acc = 0;
        for (int b = 0; b < nb; ++b) { int v = bsums[b]; bsums[b] = acc; acc += v; }
    }
}

__global__ void k_scan_add(int* __restrict__ offsets, const int* __restrict__ bsums, int n) {
    int gid = blockIdx.x * 1024 + threadIdx.x;
    if (gid < n) offsets[gid + 1] += bsums[blockIdx.x];
    if (gid == 0) offsets[0] = 0;
}

// ---------------- CSR scatter ----------------
__global__ void k_scatter(const int* __restrict__ esrc, const int* __restrict__ edst,
                          const float* __restrict__ dinv, int* __restrict__ cursor,
                          int* __restrict__ csr_src, float* __restrict__ csr_w) {
    int e = blockIdx.x * blockDim.x + threadIdx.x;
    if (e >= N_EDGES) return;
    int s = esrc[e], d = edst[e];
    int pos = atomicAdd(&cursor[d], 1);
    csr_src[pos] = s;
    csr_w[pos]   = dinv[s] * dinv[d];
}

// ---------------- diffusion: y = 0.5*(x + agg), agg includes self loop ----------------
__global__ __launch_bounds__(256) void k_diffuse3(
    const float* __restrict__ xin, float* __restrict__ xout,
    const int* __restrict__ offs, const int* __restrict__ csrc,
    const float* __restrict__ cw, const float* __restrict__ dinv) {
    int i = blockIdx.x * blockDim.x + threadIdx.x;
    if (i >= N_NODES) return;
    float di = dinv[i];
    float sw = 1.0f + di * di;
    float a0 = sw * xin[i * 3 + 0];
    float a1 = sw * xin[i * 3 + 1];
    float a2 = sw * xin[i * 3 + 2];
    int b = offs[i], e = offs[i + 1];
    for (int p = b; p < e; ++p) {
        int s = csrc[p];
        float w = cw[p];
        const float* xs = xin + (size_t)s * 3;
        a0 += w * xs[0];
        a1 += w * xs[1];
        a2 += w * xs[2];
    }
    xout[i * 3 + 0] = 0.5f * a0;
    xout[i * 3 + 1] = 0.5f * a1;
    xout[i * 3 + 2] = 0.5f * a2;
}

__global__ __launch_bounds__(256) void k_diffuse12(
    const float4* __restrict__ xin, float4* __restrict__ xout,
    const int* __restrict__ offs, const int* __restrict__ csrc,
    const float* __restrict__ cw, const float* __restrict__ dinv) {
    int i = blockIdx.x * blockDim.x + threadIdx.x;
    if (i >= N_NODES) return;
    float di = dinv[i];
    float sw = 1.0f + di * di;
    float4 q0 = xin[i * 3 + 0], q1 = xin[i * 3 + 1], q2 = xin[i * 3 + 2];
    float a[12];
    a[0] = sw * q0.x; a[1] = sw * q0.y; a[2]  = sw * q0.z; a[3]  = sw * q0.w;
    a[4] = sw * q1.x; a[5] = sw * q1.y; a[6]  = sw * q1.z; a[7]  = sw * q1.w;
    a[8] = sw * q2.x; a[9] = sw * q2.y; a[10] = sw * q2.z; a[11] = sw * q2.w;
    int b = offs[i], e = offs[i + 1];
    for (int p = b; p < e; ++p) {
        int s = csrc[p];
        float w = cw[p];
        float4 b0 = xin[s * 3 + 0], b1 = xin[s * 3 + 1], b2 = xin[s * 3 + 2];
        a[0] += w * b0.x; a[1] += w * b0.y; a[2]  += w * b0.z; a[3]  += w * b0.w;
        a[4] += w * b1.x; a[5] += w * b1.y; a[6]  += w * b1.z; a[7]  += w * b1.w;
        a[8] += w * b2.x; a[9] += w * b2.y; a[10] += w * b2.z; a[11] += w * b2.w;
    }
    float4 o0 = make_float4(0.5f*a[0], 0.5f*a[1], 0.5f*a[2],  0.5f*a[3]);
    float4 o1 = make_float4(0.5f*a[4], 0.5f*a[5], 0.5f*a[6],  0.5f*a[7]);
    float4 o2 = make_float4(0.5f*a[8], 0.5f*a[9], 0.5f*a[10], 0.5f*a[11]);
    xout[i * 3 + 0] = o0;
    xout[i * 3 + 1] = o1;
    xout[i * 3 + 2] = o2;
}

// ---------------- s1 = |wavelet differences of pass-1 levels| ----------------
__global__ void k_s1(const float* __restrict__ L1, const float* __restrict__ L2,
                     const float* __restrict__ L4, const float* __restrict__ L8,
                     const float* __restrict__ L16, float* __restrict__ s1) {
    int i = blockIdx.x * blockDim.x + threadIdx.x;
    if (i >= N_NODES) return;
    const float* Ls[5] = {L1, L2, L4, L8, L16};
    // s1[i, c*4 + f] = |L[f][i,c] - L[f+1][i,c]|
    for (int c = 0; c < 3; ++c)
        for (int f = 0; f < 4; ++f)
            s1[(size_t)i * 12 + c * 4 + f] =
                fabsf(Ls[f][(size_t)i * 3 + c] - Ls[f + 1][(size_t)i * 3 + c]);
}

// ---------------- feats (N,33) ----------------
__global__ void k_feats(const float* __restrict__ x, const float* __restrict__ s1,
                        const float* __restrict__ M1, const float* __restrict__ M2,
                        const float* __restrict__ M4, const float* __restrict__ M8,
                        const float* __restrict__ M16, float* __restrict__ feats) {
    int i = blockIdx.x * blockDim.x + threadIdx.x;
    if (i >= N_NODES) return;
    float* out = feats + (size_t)i * 33;
    // r=0 : s0 = x (raw)
    out[0] = x[i * 3 + 0];
    out[1] = x[i * 3 + 1];
    out[2] = x[i * 3 + 2];
    // r=1..4 : s1[n, c, r-1]
    for (int r = 1; r <= 4; ++r)
        for (int c = 0; c < 3; ++c)
            out[r * 3 + c] = s1[(size_t)i * 12 + c * 4 + (r - 1)];
    // r=5..10 : s2[n, m, c2] = |sub2 flat idx c2*16 + FENG[m]|, flat = w*12 + cc*4 + f
    const float* Ms[5] = {M1, M2, M4, M8, M16};
    const int FENG[6] = {4, 8, 9, 12, 13, 14};
    for (int m = 0; m < 6; ++m) {
        for (int c2 = 0; c2 < 3; ++c2) {
            int idx = c2 * 16 + FENG[m];
            int w = idx / 12, rem = idx % 12, cc = rem / 4, f = rem % 4;
            float v = Ms[w][(size_t)i * 12 + cc * 4 + f] - Ms[w + 1][(size_t)i * 12 + cc * 4 + f];
            out[(5 + m) * 3 + c2] = fabsf(v);
        }
    }
}

// ---------------- per-graph moments (batch sorted -> binary search range) ----------------
static __device__ __forceinline__ int lower_bound_i(const int* __restrict__ a, int n, int key) {
    int lo = 0, hi = n;
    while (lo < hi) { int mid = (lo + hi) >> 1; if (a[mid] < key) lo = mid + 1; else hi = mid; }
    return lo;
}

__global__ __launch_bounds__(64) void k_moments_mean(
    const float* __restrict__ feats, const int* __restrict__ batch,
    float* __restrict__ meanbuf) {
    int g = blockIdx.x;
    int lo = lower_bound_i(batch, N_NODES, g);
    int hi = lower_bound_i(batch, N_NODES, g + 1);
    float acc[33];
#pragma unroll
    for (int c = 0; c < 33; ++c) acc[c] = 0.0f;
    for (int i = lo + (int)threadIdx.x; i < hi; i += 64) {
        const float* f = feats + (size_t)i * 33;
#pragma unroll
        for (int c = 0; c < 33; ++c) acc[c] += f[c];
    }
#pragma unroll
    for (int c = 0; c < 33; ++c) {
        float v = acc[c];
        for (int o = 32; o >= 1; o >>= 1) v += __shfl_down(v, o, 64);
        acc[c] = v;
    }
    if (threadIdx.x == 0) {
        float cnt = (float)((hi - lo) > 1 ? (hi - lo) : 1);
        for (int c = 0; c < 33; ++c) meanbuf[g * 33 + c] = acc[c] / cnt;
    }
}

__global__ __launch_bounds__(64) void k_moments_vs(
    const float* __restrict__ feats, const int* __restrict__ batch,
    const float* __restrict__ meanbuf, float* __restrict__ h0) {
    int g = blockIdx.x;
    int lo = lower_bound_i(batch, N_NODES, g);
    int hi = lower_bound_i(batch, N_NODES, g + 1);
    float mu[33], a2[33], a3[33];
#pragma unroll
    for (int c = 0; c < 33; ++c) { mu[c] = meanbuf[g * 33 + c]; a2[c] = 0.0f; a3[c] = 0.0f; }
    for (int i = lo + (int)threadIdx.x; i < hi; i += 64) {
        const float* f = feats + (size_t)i * 33;
#pragma unroll
        for (int c = 0; c < 33; ++c) {
            float d = f[c] - mu[c];
            float d2 = d * d;
            a2[c] += d2;
            a3[c] += d2 * d;
        }
    }
#pragma unroll
    for (int c = 0; c < 33; ++c) {
        float v2 = a2[c], v3 = a3[c];
        for (int o = 32; o >= 1; o >>= 1) {
            v2 += __shfl_down(v2, o, 64);
            v3 += __shfl_down(v3, o, 64);
        }
        a2[c] = v2; a3[c] = v3;
    }
    if (threadIdx.x == 0) {
        float cnt = (float)((hi - lo) > 1 ? (hi - lo) : 1);
        for (int c = 0; c < 33; ++c) {
            h0[g * 99 + c]      = lrelu(mu[c]);
            h0[g * 99 + 33 + c] = lrelu(a2[c] / cnt);
            h0[g * 99 + 66 + c] = lrelu(a3[c] / cnt);
        }
    }
}

// ---------------- tiny dense layers ----------------
template <bool ACT>
__global__ void k_linear(const float* __restrict__ X, const float* __restrict__ W,
                         const float* __restrict__ bias, float* __restrict__ Y,
                         int M, int K, int Nout) {
    int t = blockIdx.x * blockDim.x + threadIdx.x;
    if (t >= M * Nout) return;
    int i = t / Nout, j = t % Nout;
    float acc = bias[j];
    const float* xr = X + (size_t)i * K;
    for (int k = 0; k < K; ++k) acc += xr[k] * W[(size_t)k * Nout + j];
    Y[t] = ACT ? lrelu(acc) : acc;
}

// ---------------- host ----------------
extern "C" void kernel_launch(void* const* d_in, const int* in_sizes, int n_in,
                              void* d_out, int out_size, void* d_ws, size_t ws_size,
                              hipStream_t stream) {
    const float* x   = (const float*)d_in[0];
    const float* W1  = (const float*)d_in[1];
    const float* b1  = (const float*)d_in[2];
    const float* W2  = (const float*)d_in[3];
    const float* b2  = (const float*)d_in[4];
    const float* W3  = (const float*)d_in[5];
    const float* b3  = (const float*)d_in[6];
    const float* We  = (const float*)d_in[7];
    const float* be  = (const float*)d_in[8];
    const float* Wc  = (const float*)d_in[9];
    const float* bc  = (const float*)d_in[10];
    const int*   eix = (const int*)d_in[11];
    const int*   batch = (const int*)d_in[12];
    const int* esrc = eix;
    const int* edst = eix + N_EDGES;

    char* ws = (char*)d_ws;
    size_t off = 0;
    auto alloc = [&](size_t bytes) -> void* {
        void* p = ws + off;
        off = (off + bytes + 255) & ~(size_t)255;
        return p;
    };
    int*   counts  = (int*)alloc((size_t)N_NODES * 4);
    int*   offsets = (int*)alloc((size_t)(N_NODES + 1) * 4);
    int*   cursor  = (int*)alloc((size_t)N_NODES * 4);
    float* dinv    = (float*)alloc((size_t)N_NODES * 4);
    int*   bsums   = (int*)alloc(1024 * 4);
    int*   csr_src = (int*)alloc((size_t)N_EDGES * 4);
    float* csr_w   = (float*)alloc((size_t)N_EDGES * 4);
    float* p1[7];
    for (int i = 0; i < 7; ++i) p1[i] = (float*)alloc((size_t)N_NODES * 3 * 4);
    float* s1 = (float*)alloc((size_t)N_NODES * 12 * 4);
    float* p2[7];
    for (int i = 0; i < 7; ++i) p2[i] = (float*)alloc((size_t)N_NODES * 12 * 4);
    float* feats = (float*)alloc((size_t)N_NODES * 33 * 4);
    float* meanb = (float*)alloc((size_t)NG * 33 * 4);
    float* h0 = (float*)alloc((size_t)NG * 99 * 4);
    float* h1 = (float*)alloc((size_t)NG * 128 * 4);
    float* h2 = (float*)alloc((size_t)NG * 64 * 4);
    float* h3 = (float*)alloc((size_t)NG * 64 * 4);
    (void)ws_size; (void)in_sizes; (void)n_in; (void)out_size;

    const int TB = 256;
    const int gbN = (N_NODES + TB - 1) / TB;
    const int gbE = (N_EDGES + TB - 1) / TB;
    const int nbScan = (N_NODES + 1023) / 1024;

    // --- GCN normalization + CSR build ---
    hipLaunchKernelGGL(k_zero_i32, dim3(gbN), dim3(TB), 0, stream, counts, N_NODES);
    hipLaunchKernelGGL(k_count, dim3(gbE), dim3(TB), 0, stream, edst, counts);
    hipLaunchKernelGGL(k_dinv, dim3(gbN), dim3(TB), 0, stream, counts, dinv);
    hipLaunchKernelGGL(k_scan_block, dim3(nbScan), dim3(1024), 0, stream, counts, offsets, bsums, N_NODES);
    hipLaunchKernelGGL(k_scan_bsums, dim3(1), dim3(1), 0, stream, bsums, nbScan);
    hipLaunchKernelGGL(k_scan_add, dim3(nbScan), dim3(1024), 0, stream, offsets, bsums, N_NODES);
    hipLaunchKernelGGL(k_copy_i32, dim3(gbN), dim3(TB), 0, stream, offsets, cursor, N_NODES);
    hipLaunchKernelGGL(k_scatter, dim3(gbE), dim3(TB), 0, stream, esrc, edst, dinv, cursor, csr_src, csr_w);

    const int saveT[5] = {1, 2, 4, 8, 16};

    // --- pass 1: diffuse (N,3), save levels 1,2,4,8,16 ---
    const float* prev = x;
    float* saves1[5];
    {
        int si = 0, sc = 0;
        for (int t = 1; t <= 16; ++t) {
            float* outb;
            if (si < 5 && t == saveT[si]) { outb = p1[si]; saves1[si] = outb; ++si; }
            else { outb = p1[5 + sc]; sc ^= 1; }
            hipLaunchKernelGGL(k_diffuse3, dim3(gbN), dim3(TB), 0, stream,
                               prev, outb, offsets, csr_src, csr_w, dinv);
            prev = outb;
        }
    }
    hipLaunchKernelGGL(k_s1, dim3(gbN), dim3(TB), 0, stream,
                       saves1[0], saves1[1], saves1[2], saves1[3], saves1[4], s1);

    // --- pass 2: diffuse (N,12), save levels 1,2,4,8,16 ---
    float* saves2[5];
    {
        const float* prev2 = s1;
        int si = 0, sc = 0;
        for (int t = 1; t <= 16; ++t) {
            float* outb;
            if (si < 5 && t == saveT[si]) { outb = p2[si]; saves2[si] = outb; ++si; }
            else { outb = p2[5 + sc]; sc ^= 1; }
            hipLaunchKernelGGL(k_diffuse12, dim3(gbN), dim3(TB), 0, stream,
                               (const float4*)prev2, (float4*)outb, offsets, csr_src, csr_w, dinv);
            prev2 = outb;
        }
    }

    // --- features + moments ---
    hipLaunchKernelGGL(k_feats, dim3(gbN), dim3(TB), 0, stream,
                       x, s1, saves2[0], saves2[1], saves2[2], saves2[3], saves2[4], feats);
    hipLaunchKernelGGL(k_moments_mean, dim3(NG), dim3(64), 0, stream, feats, batch, meanb);
    hipLaunchKernelGGL(k_moments_vs, dim3(NG), dim3(64), 0, stream, feats, batch, meanb, h0);

    // --- MLP head ---
    float* emb  = (float*)d_out;            // (512,32)
    float* outp = (float*)d_out + NG * 32;  // (512,1)
    hipLaunchKernelGGL((k_linear<true>),  dim3((NG * 128 + TB - 1) / TB), dim3(TB), 0, stream, h0, W1, b1, h1, NG, 99, 128);
    hipLaunchKernelGGL((k_linear<true>),  dim3((NG * 64 + TB - 1) / TB),  dim3(TB), 0, stream, h1, W2, b2, h2, NG, 128, 64);
    hipLaunchKernelGGL((k_linear<false>), dim3((NG * 64 + TB - 1) / TB),  dim3(TB), 0, stream, h2, W3, b3, h3, NG, 64, 64);
    hipLaunchKernelGGL((k_linear<false>), dim3((NG * 32 + TB - 1) / TB),  dim3(TB), 0, stream, h3, We, be, emb, NG, 64, 32);
    hipLaunchKernelGGL((k_linear<false>), dim3((NG + TB - 1) / TB),       dim3(TB), 0, stream, emb, Wc, bc, outp, NG, 32, 1);
}

// Round 2
// 1043.277 us; speedup vs baseline: 1.2394x; 1.2394x over previous
//
#include <hip/hip_runtime.h>

// ---------------- problem constants (fixed by reference) ----------------
#define N_NODES 100000
#define N_EDGES 1600000
#define NG      512

static __device__ __forceinline__ float lrelu(float v) {
    return v >= 0.0f ? v : 0.01f * v;
}

// ---------------- setup kernels ----------------
__global__ void k_zero_i32(int* __restrict__ p, int n) {
    int i = blockIdx.x * blockDim.x + threadIdx.x;
    if (i < n) p[i] = 0;
}

__global__ void k_copy_i32(const int* __restrict__ s, int* __restrict__ d, int n) {
    int i = blockIdx.x * blockDim.x + threadIdx.x;
    if (i < n) d[i] = s[i];
}

__global__ void k_count(const int* __restrict__ dst, int* __restrict__ counts) {
    int e = blockIdx.x * blockDim.x + threadIdx.x;
    if (e < N_EDGES) atomicAdd(&counts[dst[e]], 1);
}

// dinv = 1/sqrt(deg+1); dinv2 = dinv^2; sdeg = sqrt(deg+1)
__global__ void k_dinv(const int* __restrict__ counts, float* __restrict__ dinv,
                       float* __restrict__ dinv2, float* __restrict__ sdeg) {
    int i = blockIdx.x * blockDim.x + threadIdx.x;
    if (i < N_NODES) {
        float deg = (float)(counts[i] + 1);
        float s = sqrtf(deg);
        sdeg[i] = s;
        float di = 1.0f / s;
        dinv[i] = di;
        dinv2[i] = 1.0f / deg;
    }
}

// ---------------- exclusive scan (counts -> offsets) ----------------
__global__ void k_scan_block(const int* __restrict__ counts, int* __restrict__ offsets,
                             int* __restrict__ bsums, int n) {
    __shared__ int tmp[1024];
    int gid = blockIdx.x * 1024 + threadIdx.x;
    int v = (gid < n) ? counts[gid] : 0;
    tmp[threadIdx.x] = v;
    __syncthreads();
    for (int off = 1; off < 1024; off <<= 1) {
        int t = (threadIdx.x >= off) ? tmp[threadIdx.x - off] : 0;
        __syncthreads();
        tmp[threadIdx.x] += t;
        __syncthreads();
    }
    if (gid < n) offsets[gid + 1] = tmp[threadIdx.x];
    if (threadIdx.x == 1023) bsums[blockIdx.x] = tmp[1023];
}

__global__ void k_scan_bsums(int* __restrict__ bsums, int nb) {
    if (blockIdx.x == 0 && threadIdx.x == 0) {
        int acc = 0;
        for (int b = 0; b < nb; ++b) { int v = bsums[b]; bsums[b] = acc; acc += v; }
    }
}

__global__ void k_scan_add(int* __restrict__ offsets, const int* __restrict__ bsums, int n) {
    int gid = blockIdx.x * 1024 + threadIdx.x;
    if (gid < n) offsets[gid + 1] += bsums[blockIdx.x];
    if (gid == 0) offsets[0] = 0;
}

// ---------------- CSR scatter: src index only (v-space iteration needs no weight) ----
__global__ void k_scatter(const int* __restrict__ esrc, const int* __restrict__ edst,
                          int* __restrict__ cursor, int* __restrict__ csr_src) {
    int e = blockIdx.x * blockDim.x + threadIdx.x;
    if (e >= N_EDGES) return;
    int s = esrc[e], d = edst[e];
    int pos = atomicAdd(&cursor[d], 1);
    csr_src[pos] = s;
}

// ---------------- v-space init: v = dinv .* x ----------------
__global__ void k_vinit(const float* __restrict__ x, const float* __restrict__ dinv,
                        float* __restrict__ v) {
    int t = blockIdx.x * blockDim.x + threadIdx.x;
    if (t >= N_NODES * 3) return;
    int i = t / 3;
    v[t] = dinv[i] * x[t];
}

// ---------------- diffusion (v-space): v' = 0.5*(v + dinv2*(sum_nbr + v)) --------
// pass 1: 3 channels, 4 edge-split lanes per node -> 400K threads
__global__ __launch_bounds__(256) void k_vdiff3(
    const float* __restrict__ xin, float* __restrict__ xout,
    const int* __restrict__ offs, const int* __restrict__ csrc,
    const float* __restrict__ dinv2) {
    int t = blockIdx.x * 256 + threadIdx.x;
    if (t >= N_NODES * 4) return;
    int h = t & 3;
    int i = t >> 2;
    int b = offs[i], e = offs[i + 1];
    float a0 = 0.0f, a1 = 0.0f, a2 = 0.0f;
    for (int p = b + h; p < e; p += 4) {
        int s = csrc[p];
        const float* xs = xin + (size_t)s * 3;
        a0 += xs[0]; a1 += xs[1]; a2 += xs[2];
    }
    a0 += __shfl_xor(a0, 1, 64); a1 += __shfl_xor(a1, 1, 64); a2 += __shfl_xor(a2, 1, 64);
    a0 += __shfl_xor(a0, 2, 64); a1 += __shfl_xor(a1, 2, 64); a2 += __shfl_xor(a2, 2, 64);
    if (h == 0) {
        float d2 = dinv2[i];
        const float* xs = xin + (size_t)i * 3;
        float s0 = xs[0], s1 = xs[1], s2 = xs[2];
        xout[i * 3 + 0] = 0.5f * (s0 + d2 * (a0 + s0));
        xout[i * 3 + 1] = 0.5f * (s1 + d2 * (a1 + s1));
        xout[i * 3 + 2] = 0.5f * (s2 + d2 * (a2 + s2));
    }
}

// pass 2: 12 channels = 3 float4 quads, (quad q, edge-half h) -> 6 threads/node, 600K total
__global__ __launch_bounds__(256) void k_vdiff12(
    const float4* __restrict__ xin, float4* __restrict__ xout,
    const int* __restrict__ offs, const int* __restrict__ csrc,
    const float* __restrict__ dinv2) {
    int t = blockIdx.x * 256 + threadIdx.x;
    if (t >= N_NODES * 6) return;
    int h = t & 1;
    int rem = t % 6;
    int q = rem >> 1;
    int i = t / 6;
    int b = offs[i], e = offs[i + 1];
    float4 acc = make_float4(0.f, 0.f, 0.f, 0.f);
    for (int p = b + h; p < e; p += 2) {
        int s = csrc[p];
        float4 xv = xin[(size_t)s * 3 + q];
        acc.x += xv.x; acc.y += xv.y; acc.z += xv.z; acc.w += xv.w;
    }
    acc.x += __shfl_xor(acc.x, 1, 64);
    acc.y += __shfl_xor(acc.y, 1, 64);
    acc.z += __shfl_xor(acc.z, 1, 64);
    acc.w += __shfl_xor(acc.w, 1, 64);
    if (h == 0) {
        float d2 = dinv2[i];
        float4 sv = xin[(size_t)i * 3 + q];
        float4 o;
        o.x = 0.5f * (sv.x + d2 * (acc.x + sv.x));
        o.y = 0.5f * (sv.y + d2 * (acc.y + sv.y));
        o.z = 0.5f * (sv.z + d2 * (acc.z + sv.z));
        o.w = 0.5f * (sv.w + d2 * (acc.w + sv.w));
        xout[(size_t)i * 3 + q] = o;
    }
}

// ---------------- s1 in v-space: |vL[f]-vL[f+1]|  (dinv*sdeg factors cancel) ------
__global__ void k_s1v(const float* __restrict__ L1, const float* __restrict__ L2,
                      const float* __restrict__ L4, const float* __restrict__ L8,
                      const float* __restrict__ L16, float* __restrict__ s1v) {
    int i = blockIdx.x * blockDim.x + threadIdx.x;
    if (i >= N_NODES) return;
    const float* Ls[5] = {L1, L2, L4, L8, L16};
    for (int c = 0; c < 3; ++c)
        for (int f = 0; f < 4; ++f)
            s1v[(size_t)i * 12 + c * 4 + f] =
                fabsf(Ls[f][(size_t)i * 3 + c] - Ls[f + 1][(size_t)i * 3 + c]);
}

// ---------------- feats (N,33), converting v-space -> x-space via sdeg -----------
__global__ void k_feats(const float* __restrict__ x, const float* __restrict__ s1v,
                        const float* __restrict__ M1, const float* __restrict__ M2,
                        const float* __restrict__ M4, const float* __restrict__ M8,
                        const float* __restrict__ M16, const float* __restrict__ sdeg,
                        float* __restrict__ feats) {
    int i = blockIdx.x * blockDim.x + threadIdx.x;
    if (i >= N_NODES) return;
    float sd = sdeg[i];
    float* out = feats + (size_t)i * 33;
    out[0] = x[i * 3 + 0];
    out[1] = x[i * 3 + 1];
    out[2] = x[i * 3 + 2];
    // r=1..4 : s1_x[n, c, r-1] = sdeg * s1v[n, c*4 + (r-1)]
    for (int r = 1; r <= 4; ++r)
        for (int c = 0; c < 3; ++c)
            out[r * 3 + c] = sd * s1v[(size_t)i * 12 + c * 4 + (r - 1)];
    // r=5..10 : s2[n, m, c2]; flat idx = c2*16 + FENG[m]; flat = w*12 + cc*4 + f
    const float* Ms[5] = {M1, M2, M4, M8, M16};
    const int FENG[6] = {4, 8, 9, 12, 13, 14};
    for (int m = 0; m < 6; ++m) {
        for (int c2 = 0; c2 < 3; ++c2) {
            int idx = c2 * 16 + FENG[m];
            int w = idx / 12, rem = idx % 12, cc = rem / 4, f = rem % 4;
            float v = Ms[w][(size_t)i * 12 + cc * 4 + f] - Ms[w + 1][(size_t)i * 12 + cc * 4 + f];
            out[(5 + m) * 3 + c2] = fabsf(sd * v);
        }
    }
}

// ---------------- per-graph moments (batch sorted -> binary search range) --------
static __device__ __forceinline__ int lower_bound_i(const int* __restrict__ a, int n, int key) {
    int lo = 0, hi = n;
    while (lo < hi) { int mid = (lo + hi) >> 1; if (a[mid] < key) lo = mid + 1; else hi = mid; }
    return lo;
}

__global__ __launch_bounds__(256) void k_moments_mean(
    const float* __restrict__ feats, const int* __restrict__ batch,
    float* __restrict__ meanbuf) {
    __shared__ float part[4][33];
    int g = blockIdx.x;
    int lo = lower_bound_i(batch, N_NODES, g);
    int hi = lower_bound_i(batch, N_NODES, g + 1);
    float acc[33];
#pragma unroll
    for (int c = 0; c < 33; ++c) acc[c] = 0.0f;
    for (int i = lo + (int)threadIdx.x; i < hi; i += 256) {
        const float* f = feats + (size_t)i * 33;
#pragma unroll
        for (int c = 0; c < 33; ++c) acc[c] += f[c];
    }
#pragma unroll
    for (int c = 0; c < 33; ++c) {
        float v = acc[c];
        for (int o = 32; o >= 1; o >>= 1) v += __shfl_down(v, o, 64);
        acc[c] = v;
    }
    int wid = threadIdx.x >> 6, lane = threadIdx.x & 63;
    if (lane == 0)
        for (int c = 0; c < 33; ++c) part[wid][c] = acc[c];
    __syncthreads();
    if (threadIdx.x < 33) {
        float cnt = (float)((hi - lo) > 1 ? (hi - lo) : 1);
        float s = part[0][threadIdx.x] + part[1][threadIdx.x] +
                  part[2][threadIdx.x] + part[3][threadIdx.x];
        meanbuf[g * 33 + threadIdx.x] = s / cnt;
    }
}

__global__ __launch_bounds__(256) void k_moments_vs(
    const float* __restrict__ feats, const int* __restrict__ batch,
    const float* __restrict__ meanbuf, float* __restrict__ h0) {
    __shared__ float part2[4][33];
    __shared__ float part3[4][33];
    int g = blockIdx.x;
    int lo = lower_bound_i(batch, N_NODES, g);
    int hi = lower_bound_i(batch, N_NODES, g + 1);
    float mu[33], a2[33], a3[33];
#pragma unroll
    for (int c = 0; c < 33; ++c) { mu[c] = meanbuf[g * 33 + c]; a2[c] = 0.0f; a3[c] = 0.0f; }
    for (int i = lo + (int)threadIdx.x; i < hi; i += 256) {
        const float* f = feats + (size_t)i * 33;
#pragma unroll
        for (int c = 0; c < 33; ++c) {
            float d = f[c] - mu[c];
            float d2 = d * d;
            a2[c] += d2;
            a3[c] += d2 * d;
        }
    }
#pragma unroll
    for (int c = 0; c < 33; ++c) {
        float v2 = a2[c], v3 = a3[c];
        for (int o = 32; o >= 1; o >>= 1) {
            v2 += __shfl_down(v2, o, 64);
            v3 += __shfl_down(v3, o, 64);
        }
        a2[c] = v2; a3[c] = v3;
    }
    int wid = threadIdx.x >> 6, lane = threadIdx.x & 63;
    if (lane == 0)
        for (int c = 0; c < 33; ++c) { part2[wid][c] = a2[c]; part3[wid][c] = a3[c]; }
    __syncthreads();
    if (threadIdx.x < 33) {
        int c = threadIdx.x;
        float cnt = (float)((hi - lo) > 1 ? (hi - lo) : 1);
        float v2 = part2[0][c] + part2[1][c] + part2[2][c] + part2[3][c];
        float v3 = part3[0][c] + part3[1][c] + part3[2][c] + part3[3][c];
        h0[g * 99 + c]      = lrelu(mu[c]);
        h0[g * 99 + 33 + c] = lrelu(v2 / cnt);
        h0[g * 99 + 66 + c] = lrelu(v3 / cnt);
    }
}

// ---------------- tiny dense layers ----------------
template <bool ACT>
__global__ void k_linear(const float* __restrict__ X, const float* __restrict__ W,
                         const float* __restrict__ bias, float* __restrict__ Y,
                         int M, int K, int Nout) {
    int t = blockIdx.x * blockDim.x + threadIdx.x;
    if (t >= M * Nout) return;
    int i = t / Nout, j = t % Nout;
    float acc = bias[j];
    const float* xr = X + (size_t)i * K;
    for (int k = 0; k < K; ++k) acc += xr[k] * W[(size_t)k * Nout + j];
    Y[t] = ACT ? lrelu(acc) : acc;
}

// ---------------- host ----------------
extern "C" void kernel_launch(void* const* d_in, const int* in_sizes, int n_in,
                              void* d_out, int out_size, void* d_ws, size_t ws_size,
                              hipStream_t stream) {
    const float* x   = (const float*)d_in[0];
    const float* W1  = (const float*)d_in[1];
    const float* b1  = (const float*)d_in[2];
    const float* W2  = (const float*)d_in[3];
    const float* b2  = (const float*)d_in[4];
    const float* W3  = (const float*)d_in[5];
    const float* b3  = (const float*)d_in[6];
    const float* We  = (const float*)d_in[7];
    const float* be  = (const float*)d_in[8];
    const float* Wc  = (const float*)d_in[9];
    const float* bc  = (const float*)d_in[10];
    const int*   eix = (const int*)d_in[11];
    const int*   batch = (const int*)d_in[12];
    const int* esrc = eix;
    const int* edst = eix + N_EDGES;

    char* ws = (char*)d_ws;
    size_t off = 0;
    auto alloc = [&](size_t bytes) -> void* {
        void* p = ws + off;
        off = (off + bytes + 255) & ~(size_t)255;
        return p;
    };
    int*   counts  = (int*)alloc((size_t)N_NODES * 4);
    int*   offsets = (int*)alloc((size_t)(N_NODES + 1) * 4);
    int*   cursor  = (int*)alloc((size_t)N_NODES * 4);
    float* dinv    = (float*)alloc((size_t)N_NODES * 4);
    float* dinv2   = (float*)alloc((size_t)N_NODES * 4);
    float* sdeg    = (float*)alloc((size_t)N_NODES * 4);
    int*   bsums   = (int*)alloc(1024 * 4);
    int*   csr_src = (int*)alloc((size_t)N_EDGES * 4);
    float* v0      = (float*)alloc((size_t)N_NODES * 3 * 4);
    float* p1[7];
    for (int i = 0; i < 7; ++i) p1[i] = (float*)alloc((size_t)N_NODES * 3 * 4);
    float* s1v = (float*)alloc((size_t)N_NODES * 12 * 4);
    float* p2[7];
    for (int i = 0; i < 7; ++i) p2[i] = (float*)alloc((size_t)N_NODES * 12 * 4);
    float* feats = (float*)alloc((size_t)N_NODES * 33 * 4);
    float* meanb = (float*)alloc((size_t)NG * 33 * 4);
    float* h0 = (float*)alloc((size_t)NG * 99 * 4);
    float* h1 = (float*)alloc((size_t)NG * 128 * 4);
    float* h2 = (float*)alloc((size_t)NG * 64 * 4);
    float* h3 = (float*)alloc((size_t)NG * 64 * 4);
    (void)ws_size; (void)in_sizes; (void)n_in; (void)out_size;

    const int TB = 256;
    const int gbN = (N_NODES + TB - 1) / TB;
    const int gbE = (N_EDGES + TB - 1) / TB;
    const int nbScan = (N_NODES + 1023) / 1024;

    // --- GCN normalization + CSR build ---
    hipLaunchKernelGGL(k_zero_i32, dim3(gbN), dim3(TB), 0, stream, counts, N_NODES);
    hipLaunchKernelGGL(k_count, dim3(gbE), dim3(TB), 0, stream, edst, counts);
    hipLaunchKernelGGL(k_dinv, dim3(gbN), dim3(TB), 0, stream, counts, dinv, dinv2, sdeg);
    hipLaunchKernelGGL(k_scan_block, dim3(nbScan), dim3(1024), 0, stream, counts, offsets, bsums, N_NODES);
    hipLaunchKernelGGL(k_scan_bsums, dim3(1), dim3(1), 0, stream, bsums, nbScan);
    hipLaunchKernelGGL(k_scan_add, dim3(nbScan), dim3(1024), 0, stream, offsets, bsums, N_NODES);
    hipLaunchKernelGGL(k_copy_i32, dim3(gbN), dim3(TB), 0, stream, offsets, cursor, N_NODES);
    hipLaunchKernelGGL(k_scatter, dim3(gbE), dim3(TB), 0, stream, esrc, edst, cursor, csr_src);

    // --- v-space init ---
    hipLaunchKernelGGL(k_vinit, dim3((N_NODES * 3 + TB - 1) / TB), dim3(TB), 0, stream, x, dinv, v0);

    const int saveT[5] = {1, 2, 4, 8, 16};

    // --- pass 1: diffuse (N,3) in v-space, save levels 1,2,4,8,16 ---
    const float* prev = v0;
    float* saves1[5];
    {
        int si = 0, sc = 0;
        const int gb = (N_NODES * 4 + TB - 1) / TB;
        for (int t = 1; t <= 16; ++t) {
            float* outb;
            if (si < 5 && t == saveT[si]) { outb = p1[si]; saves1[si] = outb; ++si; }
            else { outb = p1[5 + sc]; sc ^= 1; }
            hipLaunchKernelGGL(k_vdiff3, dim3(gb), dim3(TB), 0, stream,
                               prev, outb, offsets, csr_src, dinv2);
            prev = outb;
        }
    }
    hipLaunchKernelGGL(k_s1v, dim3(gbN), dim3(TB), 0, stream,
                       saves1[0], saves1[1], saves1[2], saves1[3], saves1[4], s1v);

    // --- pass 2: diffuse (N,12) in v-space, save levels 1,2,4,8,16 ---
    float* saves2[5];
    {
        const float* prev2 = s1v;  // v2_0 = dinv * s1_x = |v-differences| = s1v
        int si = 0, sc = 0;
        const int gb = (N_NODES * 6 + TB - 1) / TB;
        for (int t = 1; t <= 16; ++t) {
            float* outb;
            if (si < 5 && t == saveT[si]) { outb = p2[si]; saves2[si] = outb; ++si; }
            else { outb = p2[5 + sc]; sc ^= 1; }
            hipLaunchKernelGGL(k_vdiff12, dim3(gb), dim3(TB), 0, stream,
                               (const float4*)prev2, (float4*)outb, offsets, csr_src, dinv2);
            prev2 = outb;
        }
    }

    // --- features + moments ---
    hipLaunchKernelGGL(k_feats, dim3(gbN), dim3(TB), 0, stream,
                       x, s1v, saves2[0], saves2[1], saves2[2], saves2[3], saves2[4], sdeg, feats);
    hipLaunchKernelGGL(k_moments_mean, dim3(NG), dim3(256), 0, stream, feats, batch, meanb);
    hipLaunchKernelGGL(k_moments_vs, dim3(NG), dim3(256), 0, stream, feats, batch, meanb, h0);

    // --- MLP head ---
    float* emb  = (float*)d_out;            // (512,32)
    float* outp = (float*)d_out + NG * 32;  // (512,1)
    hipLaunchKernelGGL((k_linear<true>),  dim3((NG * 128 + TB - 1) / TB), dim3(TB), 0, stream, h0, W1, b1, h1, NG, 99, 128);
    hipLaunchKernelGGL((k_linear<true>),  dim3((NG * 64 + TB - 1) / TB),  dim3(TB), 0, stream, h1, W2, b2, h2, NG, 128, 64);
    hipLaunchKernelGGL((k_linear<false>), dim3((NG * 64 + TB - 1) / TB),  dim3(TB), 0, stream, h2, W3, b3, h3, NG, 64, 64);
    hipLaunchKernelGGL((k_linear<false>), dim3((NG * 32 + TB - 1) / TB),  dim3(TB), 0, stream, h3, We, be, emb, NG, 64, 32);
    hipLaunchKernelGGL((k_linear<false>), dim3((NG + TB - 1) / TB),       dim3(TB), 0, stream, emb, Wc, bc, outp, NG, 32, 1);
}

// Round 3
// 955.761 us; speedup vs baseline: 1.3529x; 1.0916x over previous
//
#include <hip/hip_runtime.h>

// ---------------- problem constants (fixed by reference) ----------------
#define N_NODES 100000
#define N_EDGES 1600000
#define NG      512
#define NPART   8          // XCD partitions for scatter/count
#define NPP     12500      // nodes per partition (100000/8)
#define CHUNK_E 8192       // edges per block-chunk in partitioned kernels

static __device__ __forceinline__ float lrelu(float v) {
    return v >= 0.0f ? v : 0.01f * v;
}

// ---------------- setup kernels ----------------
__global__ void k_zero_i32(int* __restrict__ p, int n) {
    int i = blockIdx.x * blockDim.x + threadIdx.x;
    if (i < n) p[i] = 0;
}

__global__ void k_copy_i32(const int* __restrict__ s, int* __restrict__ d, int n) {
    int i = blockIdx.x * blockDim.x + threadIdx.x;
    if (i < n) d[i] = s[i];
}

// partitioned degree count: block b -> partition b&7 (XCD-affine), chunk b>>3
__global__ __launch_bounds__(256) void k_count_part(const int* __restrict__ edst,
                                                    int* __restrict__ counts) {
    int p = blockIdx.x & (NPART - 1);
    int chunk = blockIdx.x >> 3;
    int base = chunk * CHUNK_E;
    int plo = p * NPP, phi = plo + NPP;
    int end = base + CHUNK_E; if (end > N_EDGES) end = N_EDGES;
    for (int e = base + (int)threadIdx.x; e < end; e += 256) {
        int d = edst[e];
        if (d >= plo && d < phi) atomicAdd(&counts[d], 1);
    }
}

// dinv = 1/sqrt(deg+1); dinv2 = 1/(deg+1); sdeg = sqrt(deg+1)
__global__ void k_dinv(const int* __restrict__ counts, float* __restrict__ dinv,
                       float* __restrict__ dinv2, float* __restrict__ sdeg) {
    int i = blockIdx.x * blockDim.x + threadIdx.x;
    if (i < N_NODES) {
        float deg = (float)(counts[i] + 1);
        float s = sqrtf(deg);
        sdeg[i] = s;
        dinv[i] = 1.0f / s;
        dinv2[i] = 1.0f / deg;
    }
}

// ---------------- exclusive scan (counts -> offsets) ----------------
__global__ void k_scan_block(const int* __restrict__ counts, int* __restrict__ offsets,
                             int* __restrict__ bsums, int n) {
    __shared__ int tmp[1024];
    int gid = blockIdx.x * 1024 + threadIdx.x;
    int v = (gid < n) ? counts[gid] : 0;
    tmp[threadIdx.x] = v;
    __syncthreads();
    for (int off = 1; off < 1024; off <<= 1) {
        int t = (threadIdx.x >= off) ? tmp[threadIdx.x - off] : 0;
        __syncthreads();
        tmp[threadIdx.x] += t;
        __syncthreads();
    }
    if (gid < n) offsets[gid + 1] = tmp[threadIdx.x];
    if (threadIdx.x == 1023) bsums[blockIdx.x] = tmp[1023];
}

__global__ void k_scan_bsums(int* __restrict__ bsums, int nb) {
    if (blockIdx.x == 0 && threadIdx.x == 0) {
        int acc = 0;
        for (int b = 0; b < nb; ++b) { int v = bsums[b]; bsums[b] = acc; acc += v; }
    }
}

__global__ void k_scan_add(int* __restrict__ offsets, const int* __restrict__ bsums, int n) {
    int gid = blockIdx.x * 1024 + threadIdx.x;
    if (gid < n) offsets[gid + 1] += bsums[blockIdx.x];
    if (gid == 0) offsets[0] = 0;
}

// partitioned CSR scatter: writes for partition p confined to one XCD's L2
__global__ __launch_bounds__(256) void k_scatter_part(
    const int* __restrict__ esrc, const int* __restrict__ edst,
    int* __restrict__ cursor, int* __restrict__ csr_src) {
    int p = blockIdx.x & (NPART - 1);
    int chunk = blockIdx.x >> 3;
    int base = chunk * CHUNK_E;
    int plo = p * NPP, phi = plo + NPP;
    int end = base + CHUNK_E; if (end > N_EDGES) end = N_EDGES;
    for (int e = base + (int)threadIdx.x; e < end; e += 256) {
        int d = edst[e];
        if (d >= plo && d < phi) {
            int pos = atomicAdd(&cursor[d], 1);
            csr_src[pos] = esrc[e];
        }
    }
}

// ---------------- v-space init: v = dinv .* x, padded to float4 ----------------
__global__ void k_vinit(const float* __restrict__ x, const float* __restrict__ dinv,
                        float4* __restrict__ v) {
    int i = blockIdx.x * blockDim.x + threadIdx.x;
    if (i >= N_NODES) return;
    float di = dinv[i];
    v[i] = make_float4(di * x[i * 3 + 0], di * x[i * 3 + 1], di * x[i * 3 + 2], 0.0f);
}

// ---------------- diffusion (v-space): v' = 0.5*(v + dinv2*(sum_nbr + v)) --------
// pass 1: float4 node state, 4 edge-split lanes per node -> 400K threads
__global__ __launch_bounds__(256) void k_vdiff3(
    const float4* __restrict__ xin, float4* __restrict__ xout,
    const int* __restrict__ offs, const int* __restrict__ csrc,
    const float* __restrict__ dinv2) {
    int t = blockIdx.x * 256 + threadIdx.x;
    if (t >= N_NODES * 4) return;
    int h = t & 3;
    int i = t >> 2;
    int b = offs[i], e = offs[i + 1];
    float a0 = 0.0f, a1 = 0.0f, a2 = 0.0f;
    for (int p = b + h; p < e; p += 4) {
        int s = csrc[p];
        float4 xv = xin[s];
        a0 += xv.x; a1 += xv.y; a2 += xv.z;
    }
    a0 += __shfl_xor(a0, 1, 64); a1 += __shfl_xor(a1, 1, 64); a2 += __shfl_xor(a2, 1, 64);
    a0 += __shfl_xor(a0, 2, 64); a1 += __shfl_xor(a1, 2, 64); a2 += __shfl_xor(a2, 2, 64);
    if (h == 0) {
        float d2 = dinv2[i];
        float4 sv = xin[i];
        xout[i] = make_float4(0.5f * (sv.x + d2 * (a0 + sv.x)),
                              0.5f * (sv.y + d2 * (a1 + sv.y)),
                              0.5f * (sv.z + d2 * (a2 + sv.z)), 0.0f);
    }
}

// pass 2: 12 channels per thread, 4 edge-split lanes per node -> 400K threads
__global__ __launch_bounds__(256) void k_vdiff12(
    const float4* __restrict__ xin, float4* __restrict__ xout,
    const int* __restrict__ offs, const int* __restrict__ csrc,
    const float* __restrict__ dinv2) {
    int t = blockIdx.x * 256 + threadIdx.x;
    if (t >= N_NODES * 4) return;
    int h = t & 3;
    int i = t >> 2;
    int b = offs[i], e = offs[i + 1];
    float a[12];
#pragma unroll
    for (int c = 0; c < 12; ++c) a[c] = 0.0f;
    for (int p = b + h; p < e; p += 4) {
        int s = csrc[p];
        float4 b0 = xin[s * 3 + 0];
        float4 b1 = xin[s * 3 + 1];
        float4 b2 = xin[s * 3 + 2];
        a[0] += b0.x; a[1] += b0.y; a[2]  += b0.z; a[3]  += b0.w;
        a[4] += b1.x; a[5] += b1.y; a[6]  += b1.z; a[7]  += b1.w;
        a[8] += b2.x; a[9] += b2.y; a[10] += b2.z; a[11] += b2.w;
    }
#pragma unroll
    for (int c = 0; c < 12; ++c) {
        a[c] += __shfl_xor(a[c], 1, 64);
        a[c] += __shfl_xor(a[c], 2, 64);
    }
    if (h == 0) {
        float d2 = dinv2[i];
        float4 s0 = xin[i * 3 + 0], s1 = xin[i * 3 + 1], s2 = xin[i * 3 + 2];
        xout[i * 3 + 0] = make_float4(0.5f * (s0.x + d2 * (a[0] + s0.x)),
                                      0.5f * (s0.y + d2 * (a[1] + s0.y)),
                                      0.5f * (s0.z + d2 * (a[2] + s0.z)),
                                      0.5f * (s0.w + d2 * (a[3] + s0.w)));
        xout[i * 3 + 1] = make_float4(0.5f * (s1.x + d2 * (a[4] + s1.x)),
                                      0.5f * (s1.y + d2 * (a[5] + s1.y)),
                                      0.5f * (s1.z + d2 * (a[6] + s1.z)),
                                      0.5f * (s1.w + d2 * (a[7] + s1.w)));
        xout[i * 3 + 2] = make_float4(0.5f * (s2.x + d2 * (a[8] + s2.x)),
                                      0.5f * (s2.y + d2 * (a[9] + s2.y)),
                                      0.5f * (s2.z + d2 * (a[10] + s2.z)),
                                      0.5f * (s2.w + d2 * (a[11] + s2.w)));
    }
}

// ---------------- s1 in v-space: |vL[f]-vL[f+1]| (float4-padded levels in) -------
__global__ void k_s1v(const float4* __restrict__ L1, const float4* __restrict__ L2,
                      const float4* __restrict__ L4, const float4* __restrict__ L8,
                      const float4* __restrict__ L16, float* __restrict__ s1v) {
    int i = blockIdx.x * blockDim.x + threadIdx.x;
    if (i >= N_NODES) return;
    float4 v[5];
    v[0] = L1[i]; v[1] = L2[i]; v[2] = L4[i]; v[3] = L8[i]; v[4] = L16[i];
    float* out = s1v + (size_t)i * 12;
#pragma unroll
    for (int f = 0; f < 4; ++f) {
        out[0 * 4 + f] = fabsf(v[f].x - v[f + 1].x);
        out[1 * 4 + f] = fabsf(v[f].y - v[f + 1].y);
        out[2 * 4 + f] = fabsf(v[f].z - v[f + 1].z);
    }
}

// ---------------- feats (N,33), converting v-space -> x-space via sdeg -----------
__global__ void k_feats(const float* __restrict__ x, const float* __restrict__ s1v,
                        const float* __restrict__ M1, const float* __restrict__ M2,
                        const float* __restrict__ M4, const float* __restrict__ M8,
                        const float* __restrict__ M16, const float* __restrict__ sdeg,
                        float* __restrict__ feats) {
    int i = blockIdx.x * blockDim.x + threadIdx.x;
    if (i >= N_NODES) return;
    float sd = sdeg[i];
    float* out = feats + (size_t)i * 33;
    out[0] = x[i * 3 + 0];
    out[1] = x[i * 3 + 1];
    out[2] = x[i * 3 + 2];
    // r=1..4 : s1_x[n, c, r-1] = sdeg * s1v[n, c*4 + (r-1)]
    for (int r = 1; r <= 4; ++r)
        for (int c = 0; c < 3; ++c)
            out[r * 3 + c] = sd * s1v[(size_t)i * 12 + c * 4 + (r - 1)];
    // r=5..10 : s2[n, m, c2]; flat idx = c2*16 + FENG[m]; flat = w*12 + cc*4 + f
    const float* Ms[5] = {M1, M2, M4, M8, M16};
    const int FENG[6] = {4, 8, 9, 12, 13, 14};
    for (int m = 0; m < 6; ++m) {
        for (int c2 = 0; c2 < 3; ++c2) {
            int idx = c2 * 16 + FENG[m];
            int w = idx / 12, rem = idx % 12, cc = rem / 4, f = rem % 4;
            float v = Ms[w][(size_t)i * 12 + cc * 4 + f] - Ms[w + 1][(size_t)i * 12 + cc * 4 + f];
            out[(5 + m) * 3 + c2] = fabsf(sd * v);
        }
    }
}

// ---------------- per-graph moments (batch sorted -> binary search range) --------
static __device__ __forceinline__ int lower_bound_i(const int* __restrict__ a, int n, int key) {
    int lo = 0, hi = n;
    while (lo < hi) { int mid = (lo + hi) >> 1; if (a[mid] < key) lo = mid + 1; else hi = mid; }
    return lo;
}

__global__ __launch_bounds__(256) void k_moments_mean(
    const float* __restrict__ feats, const int* __restrict__ batch,
    float* __restrict__ meanbuf) {
    __shared__ float part[4][33];
    int g = blockIdx.x;
    int lo = lower_bound_i(batch, N_NODES, g);
    int hi = lower_bound_i(batch, N_NODES, g + 1);
    float acc[33];
#pragma unroll
    for (int c = 0; c < 33; ++c) acc[c] = 0.0f;
    for (int i = lo + (int)threadIdx.x; i < hi; i += 256) {
        const float* f = feats + (size_t)i * 33;
#pragma unroll
        for (int c = 0; c < 33; ++c) acc[c] += f[c];
    }
#pragma unroll
    for (int c = 0; c < 33; ++c) {
        float v = acc[c];
        for (int o = 32; o >= 1; o >>= 1) v += __shfl_down(v, o, 64);
        acc[c] = v;
    }
    int wid = threadIdx.x >> 6, lane = threadIdx.x & 63;
    if (lane == 0)
        for (int c = 0; c < 33; ++c) part[wid][c] = acc[c];
    __syncthreads();
    if (threadIdx.x < 33) {
        float cnt = (float)((hi - lo) > 1 ? (hi - lo) : 1);
        float s = part[0][threadIdx.x] + part[1][threadIdx.x] +
                  part[2][threadIdx.x] + part[3][threadIdx.x];
        meanbuf[g * 33 + threadIdx.x] = s / cnt;
    }
}

__global__ __launch_bounds__(256) void k_moments_vs(
    const float* __restrict__ feats, const int* __restrict__ batch,
    const float* __restrict__ meanbuf, float* __restrict__ h0) {
    __shared__ float part2[4][33];
    __shared__ float part3[4][33];
    int g = blockIdx.x;
    int lo = lower_bound_i(batch, N_NODES, g);
    int hi = lower_bound_i(batch, N_NODES, g + 1);
    float mu[33], a2[33], a3[33];
#pragma unroll
    for (int c = 0; c < 33; ++c) { mu[c] = meanbuf[g * 33 + c]; a2[c] = 0.0f; a3[c] = 0.0f; }
    for (int i = lo + (int)threadIdx.x; i < hi; i += 256) {
        const float* f = feats + (size_t)i * 33;
#pragma unroll
        for (int c = 0; c < 33; ++c) {
            float d = f[c] - mu[c];
            float d2 = d * d;
            a2[c] += d2;
            a3[c] += d2 * d;
        }
    }
#pragma unroll
    for (int c = 0; c < 33; ++c) {
        float v2 = a2[c], v3 = a3[c];
        for (int o = 32; o >= 1; o >>= 1) {
            v2 += __shfl_down(v2, o, 64);
            v3 += __shfl_down(v3, o, 64);
        }
        a2[c] = v2; a3[c] = v3;
    }
    int wid = threadIdx.x >> 6, lane = threadIdx.x & 63;
    if (lane == 0)
        for (int c = 0; c < 33; ++c) { part2[wid][c] = a2[c]; part3[wid][c] = a3[c]; }
    __syncthreads();
    if (threadIdx.x < 33) {
        int c = threadIdx.x;
        float cnt = (float)((hi - lo) > 1 ? (hi - lo) : 1);
        float v2 = part2[0][c] + part2[1][c] + part2[2][c] + part2[3][c];
        float v3 = part3[0][c] + part3[1][c] + part3[2][c] + part3[3][c];
        h0[g * 99 + c]      = lrelu(mu[c]);
        h0[g * 99 + 33 + c] = lrelu(v2 / cnt);
        h0[g * 99 + 66 + c] = lrelu(v3 / cnt);
    }
}

// ---------------- tiny dense layers ----------------
template <bool ACT>
__global__ void k_linear(const float* __restrict__ X, const float* __restrict__ W,
                         const float* __restrict__ bias, float* __restrict__ Y,
                         int M, int K, int Nout) {
    int t = blockIdx.x * blockDim.x + threadIdx.x;
    if (t >= M * Nout) return;
    int i = t / Nout, j = t % Nout;
    float acc = bias[j];
    const float* xr = X + (size_t)i * K;
    for (int k = 0; k < K; ++k) acc += xr[k] * W[(size_t)k * Nout + j];
    Y[t] = ACT ? lrelu(acc) : acc;
}

// ---------------- host ----------------
extern "C" void kernel_launch(void* const* d_in, const int* in_sizes, int n_in,
                              void* d_out, int out_size, void* d_ws, size_t ws_size,
                              hipStream_t stream) {
    const float* x   = (const float*)d_in[0];
    const float* W1  = (const float*)d_in[1];
    const float* b1  = (const float*)d_in[2];
    const float* W2  = (const float*)d_in[3];
    const float* b2  = (const float*)d_in[4];
    const float* W3  = (const float*)d_in[5];
    const float* b3  = (const float*)d_in[6];
    const float* We  = (const float*)d_in[7];
    const float* be  = (const float*)d_in[8];
    const float* Wc  = (const float*)d_in[9];
    const float* bc  = (const float*)d_in[10];
    const int*   eix = (const int*)d_in[11];
    const int*   batch = (const int*)d_in[12];
    const int* esrc = eix;
    const int* edst = eix + N_EDGES;

    char* ws = (char*)d_ws;
    size_t off = 0;
    auto alloc = [&](size_t bytes) -> void* {
        void* p = ws + off;
        off = (off + bytes + 255) & ~(size_t)255;
        return p;
    };
    int*   counts  = (int*)alloc((size_t)N_NODES * 4);
    int*   offsets = (int*)alloc((size_t)(N_NODES + 1) * 4);
    int*   cursor  = (int*)alloc((size_t)N_NODES * 4);
    float* dinv    = (float*)alloc((size_t)N_NODES * 4);
    float* dinv2   = (float*)alloc((size_t)N_NODES * 4);
    float* sdeg    = (float*)alloc((size_t)N_NODES * 4);
    int*   bsums   = (int*)alloc(1024 * 4);
    int*   csr_src = (int*)alloc((size_t)N_EDGES * 4);
    float4* v0     = (float4*)alloc((size_t)N_NODES * 16);
    float4* p1[7];
    for (int i = 0; i < 7; ++i) p1[i] = (float4*)alloc((size_t)N_NODES * 16);
    float* s1v = (float*)alloc((size_t)N_NODES * 12 * 4);
    float* p2[7];
    for (int i = 0; i < 7; ++i) p2[i] = (float*)alloc((size_t)N_NODES * 12 * 4);
    float* feats = (float*)alloc((size_t)N_NODES * 33 * 4);
    float* meanb = (float*)alloc((size_t)NG * 33 * 4);
    float* h0 = (float*)alloc((size_t)NG * 99 * 4);
    float* h1 = (float*)alloc((size_t)NG * 128 * 4);
    float* h2 = (float*)alloc((size_t)NG * 64 * 4);
    float* h3 = (float*)alloc((size_t)NG * 64 * 4);
    (void)ws_size; (void)in_sizes; (void)n_in; (void)out_size;

    const int TB = 256;
    const int gbN = (N_NODES + TB - 1) / TB;
    const int nbScan = (N_NODES + 1023) / 1024;
    const int nChunks = (N_EDGES + CHUNK_E - 1) / CHUNK_E;
    const int gbPart = nChunks * NPART;

    // --- GCN normalization + CSR build (XCD-partitioned) ---
    hipLaunchKernelGGL(k_zero_i32, dim3(gbN), dim3(TB), 0, stream, counts, N_NODES);
    hipLaunchKernelGGL(k_count_part, dim3(gbPart), dim3(TB), 0, stream, edst, counts);
    hipLaunchKernelGGL(k_dinv, dim3(gbN), dim3(TB), 0, stream, counts, dinv, dinv2, sdeg);
    hipLaunchKernelGGL(k_scan_block, dim3(nbScan), dim3(1024), 0, stream, counts, offsets, bsums, N_NODES);
    hipLaunchKernelGGL(k_scan_bsums, dim3(1), dim3(1), 0, stream, bsums, nbScan);
    hipLaunchKernelGGL(k_scan_add, dim3(nbScan), dim3(1024), 0, stream, offsets, bsums, N_NODES);
    hipLaunchKernelGGL(k_copy_i32, dim3(gbN), dim3(TB), 0, stream, offsets, cursor, N_NODES);
    hipLaunchKernelGGL(k_scatter_part, dim3(gbPart), dim3(TB), 0, stream, esrc, edst, cursor, csr_src);

    // --- v-space init (float4-padded) ---
    hipLaunchKernelGGL(k_vinit, dim3(gbN), dim3(TB), 0, stream, x, dinv, v0);

    const int saveT[5] = {1, 2, 4, 8, 16};

    // --- pass 1: diffuse (N,3) in v-space, save levels 1,2,4,8,16 ---
    const float4* prev = v0;
    float4* saves1[5];
    {
        int si = 0, sc = 0;
        const int gb = (N_NODES * 4 + TB - 1) / TB;
        for (int t = 1; t <= 16; ++t) {
            float4* outb;
            if (si < 5 && t == saveT[si]) { outb = p1[si]; saves1[si] = outb; ++si; }
            else { outb = p1[5 + sc]; sc ^= 1; }
            hipLaunchKernelGGL(k_vdiff3, dim3(gb), dim3(TB), 0, stream,
                               prev, outb, offsets, csr_src, dinv2);
            prev = outb;
        }
    }
    hipLaunchKernelGGL(k_s1v, dim3(gbN), dim3(TB), 0, stream,
                       saves1[0], saves1[1], saves1[2], saves1[3], saves1[4], s1v);

    // --- pass 2: diffuse (N,12) in v-space, save levels 1,2,4,8,16 ---
    float* saves2[5];
    {
        const float* prev2 = s1v;  // v2_0 = |v-differences| = s1v (dinv factors cancel)
        int si = 0, sc = 0;
        const int gb = (N_NODES * 4 + TB - 1) / TB;
        for (int t = 1; t <= 16; ++t) {
            float* outb;
            if (si < 5 && t == saveT[si]) { outb = p2[si]; saves2[si] = outb; ++si; }
            else { outb = p2[5 + sc]; sc ^= 1; }
            hipLaunchKernelGGL(k_vdiff12, dim3(gb), dim3(TB), 0, stream,
                               (const float4*)prev2, (float4*)outb, offsets, csr_src, dinv2);
            prev2 = outb;
        }
    }

    // --- features + moments ---
    hipLaunchKernelGGL(k_feats, dim3(gbN), dim3(TB), 0, stream,
                       x, s1v, saves2[0], saves2[1], saves2[2], saves2[3], saves2[4], sdeg, feats);
    hipLaunchKernelGGL(k_moments_mean, dim3(NG), dim3(256), 0, stream, feats, batch, meanb);
    hipLaunchKernelGGL(k_moments_vs, dim3(NG), dim3(256), 0, stream, feats, batch, meanb, h0);

    // --- MLP head ---
    float* emb  = (float*)d_out;            // (512,32)
    float* outp = (float*)d_out + NG * 32;  // (512,1)
    hipLaunchKernelGGL((k_linear<true>),  dim3((NG * 128 + TB - 1) / TB), dim3(TB), 0, stream, h0, W1, b1, h1, NG, 99, 128);
    hipLaunchKernelGGL((k_linear<true>),  dim3((NG * 64 + TB - 1) / TB),  dim3(TB), 0, stream, h1, W2, b2, h2, NG, 128, 64);
    hipLaunchKernelGGL((k_linear<false>), dim3((NG * 64 + TB - 1) / TB),  dim3(TB), 0, stream, h2, W3, b3, h3, NG, 64, 64);
    hipLaunchKernelGGL((k_linear<false>), dim3((NG * 32 + TB - 1) / TB),  dim3(TB), 0, stream, h3, We, be, emb, NG, 64, 32);
    hipLaunchKernelGGL((k_linear<false>), dim3((NG + TB - 1) / TB),       dim3(TB), 0, stream, emb, Wc, bc, outp, NG, 32, 1);
}